// Round 7
// baseline (188.064 us; speedup 1.0000x reference)
//
#include <hip/hip_runtime.h>
#include <hip/hip_bf16.h>

// MyMSA: B=4 S=2048 D=1024 H=16 DH=64. fp32 in/out. bf16 MFMA, fp32 accum.
//
// convert_w: W fp32 -> bf16 once (384 KB).
// qkv_kernel: 2048 blocks (bh = bid&63 XCD-aligned, 64 tokens each), no LDS,
//   no barrier: W-fragments read from L2 per use (Wb cached per XCD), VGPR
//   kept low for 8 blocks/CU. Q,K via swapped operands (tokens on C-columns,
//   packed b64 stores along d; K rows stored with per-32-token permutation
//   t -> 16*((t&4)>>2)+4*(t>>3)+(t&3)); V via non-swapped operands (tokens on
//   C-rows -> packed b64 stores along s into V^T [bh][d][s]). Q pre-scaled by
//   0.125*log2(e) (softmax via exp2).
// attn_kernel: flash attention, 256 q/block (4 waves x 64 q), 64-key tiles,
//   SINGLE barrier per iter with double-buffered LDS: store tile i ->
//   buf[i&1]; __syncthreads; issue global prefetch of tile i+1 (drained only
//   at next iter's store -> overlaps the whole compute phase); compute from
//   buf[i&1]. S^T = K·Q^T; exp2 in regs; P^T B-frag feeds O^T = V^T·P^T
//   directly (no P LDS round-trip). l = P@ones via all-ones A-frag. out=O/l.

typedef unsigned short u16;
typedef unsigned int   u32;
typedef float  f32x4  __attribute__((ext_vector_type(4)));
typedef __bf16 bf16x4 __attribute__((ext_vector_type(4)));
typedef __bf16 bf16x8 __attribute__((ext_vector_type(8)));

#define NB 4
#define SS 2048
#define DDIM 1024
#define NH 16
#define DH 64

static __device__ __forceinline__ float fexp2(float x) {
#if __has_builtin(__builtin_amdgcn_exp2f)
    return __builtin_amdgcn_exp2f(x);
#else
    return exp2f(x);
#endif
}
static __device__ __forceinline__ bf16x4 cvt4(f32x4 v) {
    return __builtin_convertvector(v, bf16x4);   // v_cvt_pk_bf16_f32 on gfx950
}
static __device__ __forceinline__ bf16x8 cvt8(f32x4 lo, f32x4 hi) {
    return __builtin_shufflevector(cvt4(lo), cvt4(hi), 0, 1, 2, 3, 4, 5, 6, 7);
}

// ---------------- Kernel 0: W fp32 -> bf16 ----------------
__global__ __launch_bounds__(256) void convert_w(
        const float* __restrict__ Wq, const float* __restrict__ Wk,
        const float* __restrict__ Wv, u16* __restrict__ Wb) {
    const int n4 = NH * DH * DH / 4;          // 16384 f32x4 per matrix
    int i = blockIdx.x * 256 + threadIdx.x;   // 0..49151
    int m = i / n4, r = i - m * n4;
    const float* src = (m == 0 ? Wq : (m == 1 ? Wk : Wv));
    f32x4 v = *(const f32x4*)(src + (size_t)r * 4);
    *(bf16x4*)((__bf16*)Wb + (size_t)m * NH * DH * DH + (size_t)r * 4) = cvt4(v);
}

// ---------------- Kernel 1: QKV projection ----------------
// grid: 64 bh x 32 chunks = 2048 blocks, 256 threads (4 waves x 16 tokens).
__global__ __launch_bounds__(256) void qkv_kernel(
        const float* __restrict__ x, const u16* __restrict__ Wb,
        const float* __restrict__ bq, const float* __restrict__ bk,
        const float* __restrict__ bv,
        u16* __restrict__ Qw, u16* __restrict__ Kw, u16* __restrict__ Vt) {
    const int tid  = threadIdx.x;
    const int w    = tid >> 6;
    const int lane = tid & 63;
    const int quad = lane >> 4;
    const int c    = lane & 15;
    const int bid  = blockIdx.x;
    const int bh   = bid & 63;           // XCD-aligned with attn
    const int chunk = bid >> 6;          // 0..31
    const int b    = bh >> 4, h = bh & 15;
    const int sb   = chunk * 64 + w * 16;    // wave tokens: sb + c

    // X^T fragments: dual-use (B for Q/K swapped; A for V non-swapped)
    const float* xr = x + ((size_t)(b * SS + sb + c)) * DDIM + h * DH;
    bf16x8 xb[2];
    #pragma unroll
    for (int kh = 0; kh < 2; ++kh) {
        f32x4 lo = *(const f32x4*)(xr + kh*32 + quad*8);
        f32x4 hi = *(const f32x4*)(xr + kh*32 + quad*8 + 4);
        xb[kh] = cvt8(lo, hi);
    }

    const int srow = sb + c;
    const int tq = srow & 31;
    const int sK = (srow & ~31) | ((tq & 4) << 2) | ((tq >> 3) << 2) | (tq & 3);
    const size_t qkbase = (size_t)bh * SS * DH;
    const size_t vtbase = (size_t)bh * DH * SS;

    const __bf16* Wq_h = (const __bf16*)Wb + (size_t)h * DH * DH;
    const __bf16* Wk_h = Wq_h + (size_t)NH * DH * DH;
    const __bf16* Wv_h = Wk_h + (size_t)NH * DH * DH;

    // ---- Q, K: swapped operands (A = W frag from L2, B = X^T frag) ----
    #pragma unroll
    for (int m = 0; m < 2; ++m) {
        const __bf16* Wm = (m == 0) ? Wq_h : Wk_h;
        const float* bm  = ((m == 0) ? bq : bk) + h * DH;
        const float scale = (m == 0) ? 0.18033688f : 1.0f;  // 0.125*log2(e)
        u16* base = ((m == 0) ? Qw : Kw) + qkbase + (size_t)(m == 0 ? srow : sK) * DH;
        #pragma unroll
        for (int mt = 0; mt < 4; ++mt) {
            const __bf16* wr = Wm + (size_t)(mt*16 + c) * DH;
            bf16x8 a0 = *(const bf16x8*)(wr + quad*8);
            bf16x8 a1 = *(const bf16x8*)(wr + 32 + quad*8);
            f32x4 acc = {0.f, 0.f, 0.f, 0.f};
            acc = __builtin_amdgcn_mfma_f32_16x16x32_bf16(a0, xb[0], acc, 0, 0, 0);
            acc = __builtin_amdgcn_mfma_f32_16x16x32_bf16(a1, xb[1], acc, 0, 0, 0);
            f32x4 bias = *(const f32x4*)(bm + mt*16 + quad*4);
            f32x4 v = (acc + bias) * scale;
            *(bf16x4*)(base + mt*16 + quad*4) = cvt4(v);        // b64 store
        }
    }
    // ---- V: non-swapped (A = X frag, B = W frag) -> C rows = tokens ----
    #pragma unroll
    for (int nt = 0; nt < 4; ++nt) {
        const __bf16* wr = Wv_h + (size_t)(nt*16 + c) * DH;
        bf16x8 b0 = *(const bf16x8*)(wr + quad*8);
        bf16x8 b1 = *(const bf16x8*)(wr + 32 + quad*8);
        f32x4 acc = {0.f, 0.f, 0.f, 0.f};
        acc = __builtin_amdgcn_mfma_f32_16x16x32_bf16(xb[0], b0, acc, 0, 0, 0);
        acc = __builtin_amdgcn_mfma_f32_16x16x32_bf16(xb[1], b1, acc, 0, 0, 0);
        const float bias = bv[h * DH + nt*16 + c];
        f32x4 v = acc + bias;
        u16* dst = Vt + vtbase + (size_t)(nt*16 + c) * SS + sb + quad*4;
        *(bf16x4*)dst = cvt4(v);                                // b64 along s
    }
}

// ---------------- Kernel 2: flash attention ----------------
// grid: 64 * 8 = 512 blocks, 256 threads (4 waves x 64 q-rows).
#define KT 64
#define KST 72   // K_lds row stride (u16)
#define VST 72   // V_lds row stride (u16)

__global__ __launch_bounds__(256, 2) void attn_kernel(
        const u16* __restrict__ Qw, const u16* __restrict__ Kw,
        const u16* __restrict__ Vt, float* __restrict__ out) {
    __shared__ __align__(16) u16 K_lds[2][KT * KST];   // 2 x 9.2 KB
    __shared__ __align__(16) u16 V_lds[2][DH * VST];   // 2 x 9.2 KB

    const int tid  = threadIdx.x;
    const int w    = tid >> 6;
    const int lane = tid & 63;
    const int quad = lane >> 4;
    const int c    = lane & 15;
    const int bid  = blockIdx.x;
    const int bh   = bid & 63;           // XCD swizzle: same bh -> same XCD
    const int q0   = (bid >> 6) * 256;
    const int qw   = q0 + w * 64;

    const u16* Qb = Qw + (size_t)bh * SS * DH;
    const u16* Kb = Kw + (size_t)bh * SS * DH;
    const u16* Vb = Vt + (size_t)bh * DH * SS;

    // Q B-frags (n=q=c, k=d=quad*8+j), held for the whole loop
    bf16x8 qf[4][2];
    #pragma unroll
    for (int qt = 0; qt < 4; ++qt) {
        const u16* qrow = Qb + (size_t)(qw + qt*16 + c) * DH;
        qf[qt][0] = *(const bf16x8*)(qrow + quad*8);
        qf[qt][1] = *(const bf16x8*)(qrow + 32 + quad*8);
    }

    f32x4 o[4][4];      // o[dt][qt]: O^T C-frags (col=q, row=d-local)
    f32x4 lacc[4];
    #pragma unroll
    for (int qt = 0; qt < 4; ++qt) {
        lacc[qt] = (f32x4){0.f, 0.f, 0.f, 0.f};
        #pragma unroll
        for (int dt = 0; dt < 4; ++dt) o[dt][qt] = (f32x4){0.f, 0.f, 0.f, 0.f};
    }

    bf16x8 ones8;
    { union { u16 u[8]; bf16x8 v; } one;
      #pragma unroll
      for (int i = 0; i < 8; ++i) one.u[i] = 0x3F80;
      ones8 = one.v; }

    // staging: row = tid>>2 (0..63), 32 u16 cols per thread (2x uint4)
    const int strow = tid >> 2;
    const int stcol = (tid & 3) * 16;
    const int kofs  = strow * KST + stcol;
    const int vofs  = strow * VST + stcol;

    // prefetch tile 0 into regs
    uint4 kr0 = *(const uint4*)(Kb + (size_t)strow * DH + stcol);
    uint4 kr1 = *(const uint4*)(Kb + (size_t)strow * DH + stcol + 8);
    uint4 vr0 = *(const uint4*)(Vb + (size_t)strow * SS + stcol);
    uint4 vr1 = *(const uint4*)(Vb + (size_t)strow * SS + stcol + 8);

    #pragma unroll 1
    for (int t0 = 0; t0 < SS; t0 += KT) {
        const int bsel = (t0 >> 6) & 1;
        u16* Kl = K_lds[bsel];
        u16* Vl = V_lds[bsel];
        // store tile t0 (drains the prefetch vmcnt HERE, after a full
        // compute phase of overlap); other waves are reading the OTHER buf
        *(uint4*)&Kl[kofs]     = kr0;
        *(uint4*)&Kl[kofs + 8] = kr1;
        *(uint4*)&Vl[vofs]     = vr0;
        *(uint4*)&Vl[vofs + 8] = vr1;
        __syncthreads();                       // single barrier per iter
        // issue prefetch of tile t0+KT (consumed at next iter's store)
        int tn = t0 + KT; if (tn >= SS) tn = 0;    // wrap: harmless reload
        kr0 = *(const uint4*)(Kb + (size_t)(tn + strow) * DH + stcol);
        kr1 = *(const uint4*)(Kb + (size_t)(tn + strow) * DH + stcol + 8);
        vr0 = *(const uint4*)(Vb + (size_t)strow * SS + tn + stcol);
        vr1 = *(const uint4*)(Vb + (size_t)strow * SS + tn + stcol + 8);

        #pragma unroll
        for (int g = 0; g < 2; ++g) {              // two 32-key groups
            bf16x8 kfA0 = *(const bf16x8*)&Kl[(g*32 + c) * KST + quad*8];
            bf16x8 kfA1 = *(const bf16x8*)&Kl[(g*32 + c) * KST + 32 + quad*8];
            bf16x8 kfB0 = *(const bf16x8*)&Kl[(g*32 + 16 + c) * KST + quad*8];
            bf16x8 kfB1 = *(const bf16x8*)&Kl[(g*32 + 16 + c) * KST + 32 + quad*8];
            bf16x8 vf[4];
            #pragma unroll
            for (int dt = 0; dt < 4; ++dt)
                vf[dt] = *(const bf16x8*)&Vl[(dt*16 + c) * VST + g*32 + quad*8];

            #pragma unroll
            for (int qt = 0; qt < 4; ++qt) {
                f32x4 sA = {0.f,0.f,0.f,0.f}, sB = {0.f,0.f,0.f,0.f};
                sA = __builtin_amdgcn_mfma_f32_16x16x32_bf16(kfA0, qf[qt][0], sA, 0,0,0);
                sA = __builtin_amdgcn_mfma_f32_16x16x32_bf16(kfA1, qf[qt][1], sA, 0,0,0);
                sB = __builtin_amdgcn_mfma_f32_16x16x32_bf16(kfB0, qf[qt][0], sB, 0,0,0);
                sB = __builtin_amdgcn_mfma_f32_16x16x32_bf16(kfB1, qf[qt][1], sB, 0,0,0);
                // P^T = exp2(S^T): lane holds tA=8*quad+r, tB=8*quad+4+r, q=c
                f32x4 eA, eB;
                #pragma unroll
                for (int r = 0; r < 4; ++r) { eA[r] = fexp2(sA[r]); eB[r] = fexp2(sB[r]); }
                bf16x8 pf = cvt8(eA, eB);
                #pragma unroll
                for (int dt = 0; dt < 4; ++dt)
                    o[dt][qt] = __builtin_amdgcn_mfma_f32_16x16x32_bf16(vf[dt], pf, o[dt][qt], 0,0,0);
                lacc[qt] = __builtin_amdgcn_mfma_f32_16x16x32_bf16(ones8, pf, lacc[qt], 0,0,0);
            }
        }
    }

    // epilogue: lane holds token = qw + qt*16 + c, d = dt*16 + quad*4 + r
    const int b = bh >> 4, h = bh & 15;
    #pragma unroll
    for (int qt = 0; qt < 4; ++qt) {
        const float inv = 1.0f / lacc[qt][0];
        const int token = qw + qt*16 + c;
        float* orow = out + ((size_t)b * SS + token) * DDIM + h * DH;
        #pragma unroll
        for (int dt = 0; dt < 4; ++dt) {
            f32x4 vv = o[dt][qt] * inv;
            *(f32x4*)(orow + dt*16 + quad*4) = vv;
        }
    }
}

extern "C" void kernel_launch(void* const* d_in, const int* in_sizes, int n_in,
                              void* d_out, int out_size, void* d_ws, size_t ws_size,
                              hipStream_t stream) {
    const float* x  = (const float*)d_in[0];
    const float* Wq = (const float*)d_in[1];
    const float* bq = (const float*)d_in[2];
    const float* Wk = (const float*)d_in[3];
    const float* bk = (const float*)d_in[4];
    const float* Wv = (const float*)d_in[5];
    const float* bv = (const float*)d_in[6];

    // ws: Qw[bh][s][d], Kw[bh][s'][d] (s permuted per 32), Vt[bh][d][s], Wb
    u16* Qw = (u16*)d_ws;
    u16* Kw = Qw + (size_t)NB * NH * SS * DH;
    u16* Vt = Kw + (size_t)NB * NH * SS * DH;
    u16* Wb = Vt + (size_t)NB * NH * SS * DH;   // 3*16*64*64 bf16 = 384 KB

    convert_w<<<3 * NH * DH * DH / 4 / 256, 256, 0, stream>>>(Wq, Wk, Wv, Wb);
    qkv_kernel<<<64 * (SS / 64), 256, 0, stream>>>(x, Wb, bq, bk, bv, Qw, Kw, Vt);
    attn_kernel<<<64 * (SS / 256), 256, 0, stream>>>(Qw, Kw, Vt, (float*)d_out);
}

// Round 8
// 179.061 us; speedup vs baseline: 1.0503x; 1.0503x over previous
//
#include <hip/hip_runtime.h>
#include <hip/hip_bf16.h>

// MyMSA: B=4 S=2048 D=1024 H=16 DH=64. fp32 in/out. bf16 MFMA, fp32 accum.
//
// qkv_kernel (R6 version — measured best): one block per (bh, 256 tokens);
//   W staged fp32->bf16 into LDS once, W-fragments read from LDS once and
//   reused over 4 token groups. Q,K swapped operands (tokens on C-columns,
//   packed b64 stores; K rows stored with per-32-token permutation
//   t -> 16*((t&4)>>2)+4*(t>>3)+(t&3)); V non-swapped (tokens on C-rows ->
//   packed b64 stores along s into V^T [bh][d][s]). Q pre-scaled by
//   0.125*log2(e) (softmax via exp2).
// attn_kernel: flash attention, 128 q/block (4 waves x 32 q = 2 qt), 64-key
//   tiles, single-barrier double-buffered LDS. Grid 1024 -> 4 blocks/CU
//   (16 waves/CU, 4/SIMD — R7 was 2/SIMD and concurrency-starved at
//   MfmaUtil 42 + VALU 36 + ~22% dead). S^T = K·Q^T; exp2 in regs; P^T
//   B-frag feeds O^T = V^T·P^T directly. l = P@ones (all-ones A-frag).
//   out = O/l. XCD swizzle: bh = bid&63.

typedef unsigned short u16;
typedef unsigned int   u32;
typedef float  f32x4  __attribute__((ext_vector_type(4)));
typedef __bf16 bf16x4 __attribute__((ext_vector_type(4)));
typedef __bf16 bf16x8 __attribute__((ext_vector_type(8)));

#define NB 4
#define SS 2048
#define DDIM 1024
#define NH 16
#define DH 64

static __device__ __forceinline__ float fexp2(float x) {
#if __has_builtin(__builtin_amdgcn_exp2f)
    return __builtin_amdgcn_exp2f(x);
#else
    return exp2f(x);
#endif
}
static __device__ __forceinline__ bf16x4 cvt4(f32x4 v) {
    return __builtin_convertvector(v, bf16x4);   // v_cvt_pk_bf16_f32 on gfx950
}
static __device__ __forceinline__ bf16x8 cvt8(f32x4 lo, f32x4 hi) {
    return __builtin_shufflevector(cvt4(lo), cvt4(hi), 0, 1, 2, 3, 4, 5, 6, 7);
}

// ---------------- Kernel 1: QKV projection (R6 version) ----------------
// grid: 64 * 8 = 512 blocks (bh = bid&63 -> co-XCD with attn), 256 threads.
#define WST 72   // W_lds row stride (u16): 144B

__global__ __launch_bounds__(256) void qkv_kernel(
        const float* __restrict__ x,
        const float* __restrict__ Wq, const float* __restrict__ bq,
        const float* __restrict__ Wk, const float* __restrict__ bk,
        const float* __restrict__ Wv, const float* __restrict__ bv,
        u16* __restrict__ Qw, u16* __restrict__ Kw, u16* __restrict__ Vt) {
    __shared__ __align__(16) u16 W_lds[3 * DH * WST];   // 27.6 KB

    const int tid  = threadIdx.x;
    const int w    = tid >> 6;
    const int lane = tid & 63;
    const int quad = lane >> 4;
    const int c    = lane & 15;
    const int bid  = blockIdx.x;
    const int bh   = bid & 63;
    const int s0   = (bid >> 6) * 256;
    const int b    = bh >> 4, h = bh & 15;

    // stage W fp32 -> bf16 into LDS
    {
        const float* Wsrc[3] = {Wq + h*DH*DH, Wk + h*DH*DH, Wv + h*DH*DH};
        #pragma unroll
        for (int j = 0; j < 6; ++j) {
            const int m = j >> 1;
            const int chunk = ((j & 1) << 8) + tid;      // 0..511 within mat
            const float* src = Wsrc[m] + chunk * 8;
            f32x4 lo = *(const f32x4*)src;
            f32x4 hi = *(const f32x4*)(src + 4);
            const int row = chunk >> 3, c8 = chunk & 7;
            *(bf16x8*)&W_lds[(m*DH + row) * WST + c8*8] = cvt8(lo, hi);
        }
    }
    __syncthreads();

    // per-wave W fragments, read from LDS ONCE, reused over 4 token groups
    bf16x8 wf[3][4][2];
    #pragma unroll
    for (int m = 0; m < 3; ++m)
        #pragma unroll
        for (int mt = 0; mt < 4; ++mt)
            #pragma unroll
            for (int kh = 0; kh < 2; ++kh)
                wf[m][mt][kh] = *(const bf16x8*)&W_lds[(m*DH + mt*16 + c) * WST + kh*32 + quad*8];

    f32x4 biasQK[2][4];
    float biasV[4];
    #pragma unroll
    for (int mt = 0; mt < 4; ++mt) {
        biasQK[0][mt] = *(const f32x4*)(bq + h*DH + mt*16 + quad*4);
        biasQK[1][mt] = *(const f32x4*)(bk + h*DH + mt*16 + quad*4);
        biasV[mt] = bv[h*DH + mt*16 + c];
    }

    const size_t qkbase = (size_t)bh * SS * DH;
    const size_t vtbase = (size_t)bh * DH * SS;

    #pragma unroll 1
    for (int g = 0; g < 4; ++g) {
        const int sb = s0 + w*64 + g*16;      // group tokens: sb + c
        const float* xr = x + ((size_t)(b * SS + sb + c)) * DDIM + h * DH;
        bf16x8 xb[2];
        #pragma unroll
        for (int kh = 0; kh < 2; ++kh) {
            f32x4 lo = *(const f32x4*)(xr + kh*32 + quad*8);
            f32x4 hi = *(const f32x4*)(xr + kh*32 + quad*8 + 4);
            xb[kh] = cvt8(lo, hi);
        }

        const int srow = sb + c;
        const int tq = srow & 31;
        const int sK = (srow & ~31) | ((tq & 4) << 2) | ((tq >> 3) << 2) | (tq & 3);

        // Q, K: swapped operands (A = W frag, B = X^T frag)
        #pragma unroll
        for (int m = 0; m < 2; ++m) {
            const float scale = (m == 0) ? 0.18033688f : 1.0f;  // 0.125*log2(e)
            u16* base = (m == 0 ? Qw : Kw) + qkbase + (size_t)(m == 0 ? srow : sK) * DH;
            #pragma unroll
            for (int mt = 0; mt < 4; ++mt) {
                f32x4 acc = {0.f, 0.f, 0.f, 0.f};
                acc = __builtin_amdgcn_mfma_f32_16x16x32_bf16(wf[m][mt][0], xb[0], acc, 0, 0, 0);
                acc = __builtin_amdgcn_mfma_f32_16x16x32_bf16(wf[m][mt][1], xb[1], acc, 0, 0, 0);
                f32x4 v = (acc + biasQK[m][mt]) * scale;
                *(bf16x4*)(base + mt*16 + quad*4) = cvt4(v);     // b64 store
            }
        }
        // V: non-swapped (A = X frag, B = W frag) -> C rows = tokens
        #pragma unroll
        for (int nt = 0; nt < 4; ++nt) {
            f32x4 acc = {0.f, 0.f, 0.f, 0.f};
            acc = __builtin_amdgcn_mfma_f32_16x16x32_bf16(xb[0], wf[2][nt][0], acc, 0, 0, 0);
            acc = __builtin_amdgcn_mfma_f32_16x16x32_bf16(xb[1], wf[2][nt][1], acc, 0, 0, 0);
            f32x4 v = acc + biasV[nt];
            u16* dst = Vt + vtbase + (size_t)(nt*16 + c) * SS + sb + quad*4;
            *(bf16x4*)dst = cvt4(v);                             // b64 along s
        }
    }
}

// ---------------- Kernel 2: flash attention ----------------
// grid: 64 * 16 = 1024 blocks, 256 threads (4 waves x 32 q-rows).
#define KT 64
#define KST 72   // K_lds row stride (u16)
#define VST 72   // V_lds row stride (u16)

__global__ __launch_bounds__(256, 4) void attn_kernel(
        const u16* __restrict__ Qw, const u16* __restrict__ Kw,
        const u16* __restrict__ Vt, float* __restrict__ out) {
    __shared__ __align__(16) u16 K_lds[2][KT * KST];   // 2 x 9.2 KB
    __shared__ __align__(16) u16 V_lds[2][DH * VST];   // 2 x 9.2 KB

    const int tid  = threadIdx.x;
    const int w    = tid >> 6;
    const int lane = tid & 63;
    const int quad = lane >> 4;
    const int c    = lane & 15;
    const int bid  = blockIdx.x;
    const int bh   = bid & 63;           // XCD swizzle: same bh -> same XCD
    const int q0   = (bid >> 6) * 128;
    const int qw   = q0 + w * 32;        // wave's 32 q-rows (2 qt)

    const u16* Qb = Qw + (size_t)bh * SS * DH;
    const u16* Kb = Kw + (size_t)bh * SS * DH;
    const u16* Vb = Vt + (size_t)bh * DH * SS;

    // Q B-frags (n=q=c, k=d=quad*8+j)
    bf16x8 qf[2][2];
    #pragma unroll
    for (int qt = 0; qt < 2; ++qt) {
        const u16* qrow = Qb + (size_t)(qw + qt*16 + c) * DH;
        qf[qt][0] = *(const bf16x8*)(qrow + quad*8);
        qf[qt][1] = *(const bf16x8*)(qrow + 32 + quad*8);
    }

    f32x4 o[4][2];      // o[dt][qt]: O^T C-frags (col=q, row=d-local)
    f32x4 lacc[2];
    #pragma unroll
    for (int qt = 0; qt < 2; ++qt) {
        lacc[qt] = (f32x4){0.f, 0.f, 0.f, 0.f};
        #pragma unroll
        for (int dt = 0; dt < 4; ++dt) o[dt][qt] = (f32x4){0.f, 0.f, 0.f, 0.f};
    }

    bf16x8 ones8;
    { union { u16 u[8]; bf16x8 v; } one;
      #pragma unroll
      for (int i = 0; i < 8; ++i) one.u[i] = 0x3F80;
      ones8 = one.v; }

    // staging: row = tid>>2 (0..63), 32 u16 cols per thread (2x uint4)
    const int strow = tid >> 2;
    const int stcol = (tid & 3) * 16;
    const int kofs  = strow * KST + stcol;
    const int vofs  = strow * VST + stcol;

    uint4 kr0 = *(const uint4*)(Kb + (size_t)strow * DH + stcol);
    uint4 kr1 = *(const uint4*)(Kb + (size_t)strow * DH + stcol + 8);
    uint4 vr0 = *(const uint4*)(Vb + (size_t)strow * SS + stcol);
    uint4 vr1 = *(const uint4*)(Vb + (size_t)strow * SS + stcol + 8);

    #pragma unroll 1
    for (int t0 = 0; t0 < SS; t0 += KT) {
        const int bsel = (t0 >> 6) & 1;
        u16* Kl = K_lds[bsel];
        u16* Vl = V_lds[bsel];
        // store tile t0 (prefetch vmcnt drains here, after a compute phase)
        *(uint4*)&Kl[kofs]     = kr0;
        *(uint4*)&Kl[kofs + 8] = kr1;
        *(uint4*)&Vl[vofs]     = vr0;
        *(uint4*)&Vl[vofs + 8] = vr1;
        __syncthreads();                       // single barrier per iter
        int tn = t0 + KT; if (tn >= SS) tn = 0;    // wrap: harmless reload
        kr0 = *(const uint4*)(Kb + (size_t)(tn + strow) * DH + stcol);
        kr1 = *(const uint4*)(Kb + (size_t)(tn + strow) * DH + stcol + 8);
        vr0 = *(const uint4*)(Vb + (size_t)strow * SS + tn + stcol);
        vr1 = *(const uint4*)(Vb + (size_t)strow * SS + tn + stcol + 8);

        #pragma unroll
        for (int g = 0; g < 2; ++g) {              // two 32-key groups
            bf16x8 kfA0 = *(const bf16x8*)&Kl[(g*32 + c) * KST + quad*8];
            bf16x8 kfA1 = *(const bf16x8*)&Kl[(g*32 + c) * KST + 32 + quad*8];
            bf16x8 kfB0 = *(const bf16x8*)&Kl[(g*32 + 16 + c) * KST + quad*8];
            bf16x8 kfB1 = *(const bf16x8*)&Kl[(g*32 + 16 + c) * KST + 32 + quad*8];
            bf16x8 vf[4];
            #pragma unroll
            for (int dt = 0; dt < 4; ++dt)
                vf[dt] = *(const bf16x8*)&Vl[(dt*16 + c) * VST + g*32 + quad*8];

            #pragma unroll
            for (int qt = 0; qt < 2; ++qt) {
                f32x4 sA = {0.f,0.f,0.f,0.f}, sB = {0.f,0.f,0.f,0.f};
                sA = __builtin_amdgcn_mfma_f32_16x16x32_bf16(kfA0, qf[qt][0], sA, 0,0,0);
                sA = __builtin_amdgcn_mfma_f32_16x16x32_bf16(kfA1, qf[qt][1], sA, 0,0,0);
                sB = __builtin_amdgcn_mfma_f32_16x16x32_bf16(kfB0, qf[qt][0], sB, 0,0,0);
                sB = __builtin_amdgcn_mfma_f32_16x16x32_bf16(kfB1, qf[qt][1], sB, 0,0,0);
                // P^T = exp2(S^T): lane holds tA=8*quad+r, tB=8*quad+4+r, q=c
                f32x4 eA, eB;
                #pragma unroll
                for (int r = 0; r < 4; ++r) { eA[r] = fexp2(sA[r]); eB[r] = fexp2(sB[r]); }
                bf16x8 pf = cvt8(eA, eB);
                #pragma unroll
                for (int dt = 0; dt < 4; ++dt)
                    o[dt][qt] = __builtin_amdgcn_mfma_f32_16x16x32_bf16(vf[dt], pf, o[dt][qt], 0,0,0);
                lacc[qt] = __builtin_amdgcn_mfma_f32_16x16x32_bf16(ones8, pf, lacc[qt], 0,0,0);
            }
        }
    }

    // epilogue: lane holds token = qw + qt*16 + c, d = dt*16 + quad*4 + r
    const int b = bh >> 4, h = bh & 15;
    #pragma unroll
    for (int qt = 0; qt < 2; ++qt) {
        const float inv = 1.0f / lacc[qt][0];
        const int token = qw + qt*16 + c;
        float* orow = out + ((size_t)b * SS + token) * DDIM + h * DH;
        #pragma unroll
        for (int dt = 0; dt < 4; ++dt) {
            f32x4 vv = o[dt][qt] * inv;
            *(f32x4*)(orow + dt*16 + quad*4) = vv;
        }
    }
}

extern "C" void kernel_launch(void* const* d_in, const int* in_sizes, int n_in,
                              void* d_out, int out_size, void* d_ws, size_t ws_size,
                              hipStream_t stream) {
    const float* x  = (const float*)d_in[0];
    const float* Wq = (const float*)d_in[1];
    const float* bq = (const float*)d_in[2];
    const float* Wk = (const float*)d_in[3];
    const float* bk = (const float*)d_in[4];
    const float* Wv = (const float*)d_in[5];
    const float* bv = (const float*)d_in[6];

    // ws: Qw[bh][s][d], Kw[bh][s'][d] (s permuted per 32), Vt[bh][d][s]
    u16* Qw = (u16*)d_ws;
    u16* Kw = Qw + (size_t)NB * NH * SS * DH;
    u16* Vt = Kw + (size_t)NB * NH * SS * DH;

    qkv_kernel<<<64 * (SS / 256), 256, 0, stream>>>(
        x, Wq, bq, Wk, bk, Wv, bv, Qw, Kw, Vt);
    attn_kernel<<<64 * (SS / 128), 256, 0, stream>>>(Qw, Kw, Vt, (float*)d_out);
}